// Round 3
// baseline (199.334 us; speedup 1.0000x reference)
//
#include <hip/hip_runtime.h>
#include <hip/hip_fp16.h>
#include <math.h>
#include <stdint.h>

// VQ via f16x3 split MFMA (32x32x16): dot = (hi.hi + hi.lo + lo.hi) * 2^-20.
// diff = (v2 - 2*dot) + c2 fp32-rounded per np; argmin codes 1..4095, ties -> lowest n.
// R12: LDS-free main loop, 4x4 wave tile (128m x 128n per wave, 256x256 block).
// 341 B VMEM per MFMA (vs 512 at 4x2) -> under the L2-return-BW breakeven.
// 1 wave/SIMD (acc 256 + operands 128 VGPR); loads prefetched 1 kstep (1536 cy) ahead.

#define M_TOTAL 16384
#define NCODES  4096
#define D_DIM   256

#define OUT_OFF_IDX  (M_TOTAL * D_DIM)
#define OUT_OFF_LOSS (OUT_OFF_IDX + M_TOTAL)

typedef _Float16 half8 __attribute__((ext_vector_type(8)));
typedef float    float16v __attribute__((ext_vector_type(16)));

// ---- fused prep: blocks 0..255 = W (pack Bp + c2), 256..1279 = V (pack Vp + v2 + pk init) ----
// Bp element (n,k,plane): panel=n>>5, kstep=k>>4, lhi=(k>>3)&1
//   offset = (panel*16+kstep)*2048 + plane*1024 + lhi*256 + (n&31)*8 + (k&7)
// Vp element (m,k,plane): panel=m>>5, kstep=k>>4, lhi=(k>>3)&1   (tight: fits 16MB d_out)
//   offset = (panel*16+kstep)*1024 + plane*512  + lhi*256 + (m&31)*8 + (k&7)
__global__ __launch_bounds__(256) void prep_kernel(
    const float* __restrict__ V, const float* __restrict__ W,
    _Float16* __restrict__ Vp, _Float16* __restrict__ Bp,
    float* __restrict__ v2, float* __restrict__ c2,
    uint64_t* __restrict__ pk)
{
  __shared__ float T[16 * 264];
  const int t = threadIdx.x;
  const int rloc = t >> 4, seg = t & 15;
  const bool isW = blockIdx.x < 256;
  const int bid2 = isW ? blockIdx.x : (blockIdx.x - 256);
  const int row = bid2 * 16 + rloc;
  const float* X = isW ? W : V;

  if (!isW && bid2 < 64) pk[bid2 * 256 + t] = ~0ULL;   // init argmin array

  const float* src = X + (size_t)row * D_DIM + seg * 16;
  float4 x[4];
#pragma unroll
  for (int u = 0; u < 4; ++u) x[u] = ((const float4*)src)[u];
  union { half8 v; _Float16 e[8]; } uh[2], ul[2];
#pragma unroll
  for (int u = 0; u < 4; ++u) {
    float e4[4] = {x[u].x, x[u].y, x[u].z, x[u].w};
#pragma unroll
    for (int j = 0; j < 4; ++j) {
      const int e = u * 4 + j;
      float s = e4[j] * 1024.0f;            // exact pow2 scale
      _Float16 h = (_Float16)s;             // RN
      uh[e >> 3].e[e & 7] = h;
      ul[e >> 3].e[e & 7] = (_Float16)(s - (float)h);  // RN of exact residual
    }
    *(float4*)&T[rloc * 264 + seg * 16 + u * 4] = x[u];
  }
  if (isW) {
    const int panel = row >> 5, nin = row & 31;
    _Float16* dst = Bp + ((size_t)panel * 16 + seg) * 2048 + nin * 8;
#pragma unroll
    for (int lh = 0; lh < 2; ++lh) {
      *(half8*)(dst + lh * 256)        = uh[lh].v;   // hi plane
      *(half8*)(dst + 1024 + lh * 256) = ul[lh].v;   // lo plane
    }
  } else {
    _Float16* dst = Vp + ((size_t)(row >> 5) * 16 + seg) * 1024 + (row & 31) * 8;
#pragma unroll
    for (int lh = 0; lh < 2; ++lh) {
      *(half8*)(dst + lh * 256)        = uh[lh].v;   // hi plane
      *(half8*)(dst + 512 + lh * 256)  = ul[lh].v;   // lo plane
    }
  }
  __syncthreads();
  // rowsq, numpy pairwise chain order (fadd commutative -> shuffle tree exact)
  const int half = (t >> 3) & 1, j = t & 7;
  const float* tr = &T[rloc * 264 + half * 128 + j];
  float r = __fmul_rn(tr[0], tr[0]);
#pragma unroll
  for (int i = 1; i < 16; ++i) { float e = tr[8 * i]; r = __fadd_rn(r, __fmul_rn(e, e)); }
  r = __fadd_rn(r, __shfl_xor(r, 1));
  r = __fadd_rn(r, __shfl_xor(r, 2));
  r = __fadd_rn(r, __shfl_xor(r, 4));
  r = __fadd_rn(r, __shfl_xor(r, 8));   // pw(0:128) + pw(128:256)
  if ((t & 15) == 0) { if (isW) c2[row] = r; else v2[row] = r; }
}

// ---- main: block 256m x 256n, 4 waves 2x2, wave tile 128m x 128n (Tm=4, Tn=4) ----
// All operands streamed from global packed layouts; no LDS until epilogue.
__global__ __launch_bounds__(256, 1) void vq_mfma_kernel(
    const _Float16* __restrict__ Vp, const _Float16* __restrict__ Bp,
    const float* __restrict__ v2, const float* __restrict__ c2,
    uint64_t* __restrict__ pk)
{
  // epilogue-only LDS: wbuf 4 waves x 1056 u64 = 33792 B, red2[512] u64 = 4096 B
  __shared__ __align__(16) char smem_raw[37888];
  uint64_t* red2 = (uint64_t*)(smem_raw + 33792);

  const int tid  = threadIdx.x;
  const int lane = tid & 63;
  const int wave = tid >> 6;
  const int wr = wave >> 1, wc = wave & 1;
  const int l31 = lane & 31, lhi = lane >> 5;

  const int bid = blockIdx.x;
  // L2-residency swizzle: XCD (bid&7) owns mblks {xcd*8..xcd*8+7} -> 2 MB Vp slice
  // stays L2-resident; pblks swept outer, so A loads are L2 hits after warmup.
  const int xcd  = bid & 7;
  const int seq  = bid >> 3;            // 0..127
  const int mblk = xcd * 8 + (seq & 7); // 0..63
  const int pblk = seq >> 3;            // 0..15 (256 n-cols each)
  const int m0 = mblk * 256;
  const int n0 = pblk * 256;
  const int p32 = pblk * 8 + wc * 4;    // first 32-n panel for this wave
  const int mp0 = mblk * 8 + wr * 4;    // first of 4 A-panels for this wave

  // fragment base pointers (lane*8 gives lhi*256 + l31*8: row=l31, k-half=lhi)
  const _Float16* pA[4];
#pragma unroll
  for (int mb = 0; mb < 4; ++mb)
    pA[mb] = Vp + ((size_t)(mp0 + mb) * 16) * 1024 + lane * 8;
  const _Float16* pB[4];
#pragma unroll
  for (int nb = 0; nb < 4; ++nb)
    pB[nb] = Bp + ((size_t)(p32 + nb) * 16) * 2048 + lane * 8;

  float16v acc[4][4];
#pragma unroll
  for (int mb = 0; mb < 4; ++mb)
#pragma unroll
    for (int nb = 0; nb < 4; ++nb) acc[mb][nb] = (float16v)0.0f;

  half8 ah[2][4], al[2][4], bh[2][4], bl[2][4];
  // prologue: kstep 0 -> buf 0
#pragma unroll
  for (int mb = 0; mb < 4; ++mb) {
    ah[0][mb] = *(const half8*)(pA[mb]);
    al[0][mb] = *(const half8*)(pA[mb] + 512);
  }
#pragma unroll
  for (int nb = 0; nb < 4; ++nb) {
    bh[0][nb] = *(const half8*)(pB[nb]);
    bl[0][nb] = *(const half8*)(pB[nb] + 1024);
  }

#pragma unroll
  for (int kstep = 0; kstep < 16; ++kstep) {
    const int cur = kstep & 1, nxt = cur ^ 1;
    if (kstep < 15) {                        // prefetch next kstep into other buffer
      const int ko = kstep + 1;
#pragma unroll
      for (int mb = 0; mb < 4; ++mb) {
        const _Float16* p = pA[mb] + ko * 1024;
        ah[nxt][mb] = *(const half8*)p;
        al[nxt][mb] = *(const half8*)(p + 512);
      }
#pragma unroll
      for (int nb = 0; nb < 4; ++nb) {
        const _Float16* p = pB[nb] + ko * 2048;
        bh[nxt][nb] = *(const half8*)p;
        bl[nxt][nb] = *(const half8*)(p + 1024);
      }
    }
    // product-major, per-acc order identical to R9/R10/R11 (bit-exact):
    // hi.hi, hi.lo, lo.hi within each kstep, ksteps ascending.
#pragma unroll
    for (int nb = 0; nb < 4; ++nb)
#pragma unroll
      for (int mb = 0; mb < 4; ++mb)
        acc[mb][nb] = __builtin_amdgcn_mfma_f32_32x32x16_f16(ah[cur][mb], bh[cur][nb], acc[mb][nb], 0, 0, 0);
#pragma unroll
    for (int nb = 0; nb < 4; ++nb)
#pragma unroll
      for (int mb = 0; mb < 4; ++mb)
        acc[mb][nb] = __builtin_amdgcn_mfma_f32_32x32x16_f16(ah[cur][mb], bl[cur][nb], acc[mb][nb], 0, 0, 0);
#pragma unroll
    for (int nb = 0; nb < 4; ++nb)
#pragma unroll
      for (int mb = 0; mb < 4; ++mb)
        acc[mb][nb] = __builtin_amdgcn_mfma_f32_32x32x16_f16(al[cur][mb], bh[cur][nb], acc[mb][nb], 0, 0, 0);
  }

  // ---- epilogue: diff = (v2 - 2*dot) + c2 (np order), argmin, tie -> lowest n ----
  float c2r[4];
#pragma unroll
  for (int nb = 0; nb < 4; ++nb) c2r[nb] = c2[n0 + wc * 128 + nb * 32 + l31];

  uint64_t* wbuf = (uint64_t*)smem_raw + wave * 1056;   // 32 rows x 33 u64, per wave

#pragma unroll
  for (int mb = 0; mb < 4; ++mb) {
#pragma unroll
    for (int r = 0; r < 16; ++r) {
      const int rowin = (r & 3) + 8 * (r >> 2) + 4 * lhi;
      const float v2m = v2[m0 + wr * 128 + mb * 32 + rowin];
      uint64_t b = ~0ULL;
#pragma unroll
      for (int nb = 0; nb < 4; ++nb) {
        const int n = n0 + wc * 128 + nb * 32 + l31;
        float dot = acc[mb][nb][r] * 0x1p-20f;            // exact pow2 unscale
        float dd  = __fadd_rn(__fsub_rn(v2m, 2.0f * dot), c2r[nb]);
        if (n == 0) dd = INFINITY;                        // exclude code 0
        uint64_t p = ((uint64_t)__float_as_uint(dd) << 32) | (uint32_t)n;
        if (p < b) b = p;                                 // dd>0 -> bits monotonic; nb asc keeps lowest n
      }
      wbuf[(r * 2 + lhi) * 33 + l31] = b;
    }
    __syncthreads();
    {
      const int f = lane >> 1, hf = lane & 1;
      const uint64_t* rp = wbuf + f * 33 + hf * 16;
      uint64_t m = rp[0];
#pragma unroll
      for (int i = 1; i < 16; ++i) { uint64_t v = rp[i]; if (v < m) m = v; }
      uint64_t o = __shfl_xor((unsigned long long)m, 1);
      if (o < m) m = o;
      if (hf == 0) {
        const int r_ = f >> 1, lh2 = f & 1;
        const int rowin = (r_ & 3) + 8 * (r_ >> 2) + 4 * lh2;
        red2[(wr * 128 + mb * 32 + rowin) * 2 + wc] = m;
      }
    }
    __syncthreads();
  }

  uint64_t a0 = red2[tid * 2], a1 = red2[tid * 2 + 1];
  atomicMin((unsigned long long*)&pk[m0 + tid], (unsigned long long)(a0 < a1 ? a0 : a1));
}

// ---- gather: one wave per query, no barriers ----
__global__ __launch_bounds__(256) void gather_kernel(
    const float* __restrict__ V, const float* __restrict__ W,
    const uint64_t* __restrict__ pk,
    float* __restrict__ out, float* __restrict__ outIdx,
    float* __restrict__ lossPartial)
{
  const int q = blockIdx.x * 4 + (threadIdx.x >> 6);
  const int l = threadIdx.x & 63;
  const uint64_t b = pk[q];             // wave-uniform broadcast load
  float4 vv = *(const float4*)(V + (size_t)q * D_DIM + l * 4);
  const float inv = 0.00390625f;
  bool ne = (vv.x != inv) | (vv.y != inv) | (vv.z != inv) | (vv.w != inv);
  const int idx = __ballot(ne) ? (int)(uint32_t)b : 0;
  float4 o4 = *(const float4*)(W + (size_t)idx * D_DIM + l * 4);
  *(float4*)(out + (size_t)q * D_DIM + l * 4) = o4;
  if (l == 0) outIdx[q] = (float)idx;
  float dx = o4.x - vv.x, dy = o4.y - vv.y, dz = o4.z - vv.z, dw = o4.w - vv.w;
  float s = dx * dx + dy * dy + dz * dz + dw * dw;
#pragma unroll
  for (int off = 32; off; off >>= 1) s += __shfl_xor(s, off);
  if (l == 0) lossPartial[q] = s;
}

__global__ __launch_bounds__(256) void finalize_kernel(
    const float* __restrict__ lossPartial, float* __restrict__ out)
{
  const int t = threadIdx.x;
  __shared__ float red[256];
  float s = 0.0f;
  for (int i = t; i < M_TOTAL; i += 256) s += lossPartial[i];
  red[t] = s;
  __syncthreads();
  for (int st = 128; st > 0; st >>= 1) {
    if (t < st) red[t] += red[t + st];
    __syncthreads();
  }
  if (t == 0) {
    out[0] = (float)((double)red[0] / (double)(M_TOTAL * D_DIM));  // loss
    out[1] = 0.0f;                                                 // used
  }
}

extern "C" void kernel_launch(void* const* d_in, const int* in_sizes, int n_in,
                              void* d_out, int out_size, void* d_ws, size_t ws_size,
                              hipStream_t stream) {
  const float* V = (const float*)d_in[0];   // 16384 x 256
  const float* W = (const float*)d_in[1];   // 4096 x 256
  float* out = (float*)d_out;

  // Packed V fragments live in d_out (exactly 16384*256*4 bytes); gather overwrites later.
  _Float16* Vp = (_Float16*)d_out;

  char* ws = (char*)d_ws;
  _Float16* Bp  = (_Float16*)(ws);                        // packed W frags: 8 MB region
  float*    c2  = (float*)(ws + 8388608);                 // 16 KB
  float*    v2  = (float*)(ws + 8388608 + 16384);         // 64 KB
  uint64_t* pk  = (uint64_t*)(ws + 8388608 + 16384 + 65536);   // 16384 u64 = 128 KB
  float* lossPartial = (float*)(ws + 8388608 + 16384 + 65536 + 131072);  // 64 KB

  prep_kernel<<<1280, 256, 0, stream>>>(V, W, Vp, Bp, v2, c2, pk);
  vq_mfma_kernel<<<1024, 256, 0, stream>>>(Vp, Bp, v2, c2, pk);
  gather_kernel<<<M_TOTAL / 4, 256, 0, stream>>>(V, W, pk, out, out + OUT_OFF_IDX, lossPartial);
  finalize_kernel<<<1, 256, 0, stream>>>(lossPartial, out + OUT_OFF_LOSS);
}

// Round 4
// 197.606 us; speedup vs baseline: 1.0087x; 1.0087x over previous
//
#include <hip/hip_runtime.h>
#include <hip/hip_fp16.h>
#include <math.h>
#include <stdint.h>

// VQ via f16x3 split MFMA (32x32x16): dot = (hi.hi + hi.lo + lo.hi) * 2^-20.
// diff = (v2 - 2*dot) + c2 fp32-rounded per np; argmin codes 1..4095, ties -> lowest n.
// R13: LDS-free main loop, 4x4 wave tile, DEPTH-2 register prefetch (3-buffer ring).
// Loads for kstep k issue at top of kstep k-2 (~3500 cy ahead) so no kstep-boundary
// vmcnt stall survives, even if the compiler reorders within one kstep.
// 1 wave/SIMD, ~490/512 VGPR. Accumulation order identical to R9-R12 (bit-exact).

#define M_TOTAL 16384
#define NCODES  4096
#define D_DIM   256

#define OUT_OFF_IDX  (M_TOTAL * D_DIM)
#define OUT_OFF_LOSS (OUT_OFF_IDX + M_TOTAL)

typedef _Float16 half8 __attribute__((ext_vector_type(8)));
typedef float    float16v __attribute__((ext_vector_type(16)));

// ---- fused prep: blocks 0..255 = W (pack Bp + c2), 256..1279 = V (pack Vp + v2 + pk init) ----
// Bp element (n,k,plane): panel=n>>5, kstep=k>>4, lhi=(k>>3)&1
//   offset = (panel*16+kstep)*2048 + plane*1024 + lhi*256 + (n&31)*8 + (k&7)
// Vp element (m,k,plane): panel=m>>5, kstep=k>>4, lhi=(k>>3)&1   (tight: fits 16MB d_out)
//   offset = (panel*16+kstep)*1024 + plane*512  + lhi*256 + (m&31)*8 + (k&7)
__global__ __launch_bounds__(256) void prep_kernel(
    const float* __restrict__ V, const float* __restrict__ W,
    _Float16* __restrict__ Vp, _Float16* __restrict__ Bp,
    float* __restrict__ v2, float* __restrict__ c2,
    uint64_t* __restrict__ pk)
{
  __shared__ float T[16 * 264];
  const int t = threadIdx.x;
  const int rloc = t >> 4, seg = t & 15;
  const bool isW = blockIdx.x < 256;
  const int bid2 = isW ? blockIdx.x : (blockIdx.x - 256);
  const int row = bid2 * 16 + rloc;
  const float* X = isW ? W : V;

  if (!isW && bid2 < 64) pk[bid2 * 256 + t] = ~0ULL;   // init argmin array

  const float* src = X + (size_t)row * D_DIM + seg * 16;
  float4 x[4];
#pragma unroll
  for (int u = 0; u < 4; ++u) x[u] = ((const float4*)src)[u];
  union { half8 v; _Float16 e[8]; } uh[2], ul[2];
#pragma unroll
  for (int u = 0; u < 4; ++u) {
    float e4[4] = {x[u].x, x[u].y, x[u].z, x[u].w};
#pragma unroll
    for (int j = 0; j < 4; ++j) {
      const int e = u * 4 + j;
      float s = e4[j] * 1024.0f;            // exact pow2 scale
      _Float16 h = (_Float16)s;             // RN
      uh[e >> 3].e[e & 7] = h;
      ul[e >> 3].e[e & 7] = (_Float16)(s - (float)h);  // RN of exact residual
    }
    *(float4*)&T[rloc * 264 + seg * 16 + u * 4] = x[u];
  }
  if (isW) {
    const int panel = row >> 5, nin = row & 31;
    _Float16* dst = Bp + ((size_t)panel * 16 + seg) * 2048 + nin * 8;
#pragma unroll
    for (int lh = 0; lh < 2; ++lh) {
      *(half8*)(dst + lh * 256)        = uh[lh].v;   // hi plane
      *(half8*)(dst + 1024 + lh * 256) = ul[lh].v;   // lo plane
    }
  } else {
    _Float16* dst = Vp + ((size_t)(row >> 5) * 16 + seg) * 1024 + (row & 31) * 8;
#pragma unroll
    for (int lh = 0; lh < 2; ++lh) {
      *(half8*)(dst + lh * 256)        = uh[lh].v;   // hi plane
      *(half8*)(dst + 512 + lh * 256)  = ul[lh].v;   // lo plane
    }
  }
  __syncthreads();
  // rowsq, numpy pairwise chain order (fadd commutative -> shuffle tree exact)
  const int half = (t >> 3) & 1, j = t & 7;
  const float* tr = &T[rloc * 264 + half * 128 + j];
  float r = __fmul_rn(tr[0], tr[0]);
#pragma unroll
  for (int i = 1; i < 16; ++i) { float e = tr[8 * i]; r = __fadd_rn(r, __fmul_rn(e, e)); }
  r = __fadd_rn(r, __shfl_xor(r, 1));
  r = __fadd_rn(r, __shfl_xor(r, 2));
  r = __fadd_rn(r, __shfl_xor(r, 4));
  r = __fadd_rn(r, __shfl_xor(r, 8));   // pw(0:128) + pw(128:256)
  if ((t & 15) == 0) { if (isW) c2[row] = r; else v2[row] = r; }
}

// ---- main: block 256m x 256n, 4 waves 2x2, wave tile 128m x 128n (Tm=4, Tn=4) ----
// All operands streamed from global packed layouts; no LDS until epilogue.
__global__ __launch_bounds__(256, 1) void vq_mfma_kernel(
    const _Float16* __restrict__ Vp, const _Float16* __restrict__ Bp,
    const float* __restrict__ v2, const float* __restrict__ c2,
    uint64_t* __restrict__ pk)
{
  // epilogue-only LDS: wbuf 4 waves x 1056 u64 = 33792 B, red2[512] u64 = 4096 B
  __shared__ __align__(16) char smem_raw[37888];
  uint64_t* red2 = (uint64_t*)(smem_raw + 33792);

  const int tid  = threadIdx.x;
  const int lane = tid & 63;
  const int wave = tid >> 6;
  const int wr = wave >> 1, wc = wave & 1;
  const int l31 = lane & 31, lhi = lane >> 5;

  const int bid = blockIdx.x;
  // L2-residency swizzle: XCD (bid&7) owns mblks {xcd*8..xcd*8+7} -> 2 MB Vp slice
  // stays L2-resident; pblks swept outer, so A loads are L2 hits after warmup.
  const int xcd  = bid & 7;
  const int seq  = bid >> 3;            // 0..127
  const int mblk = xcd * 8 + (seq & 7); // 0..63
  const int pblk = seq >> 3;            // 0..15 (256 n-cols each)
  const int m0 = mblk * 256;
  const int n0 = pblk * 256;
  const int p32 = pblk * 8 + wc * 4;    // first 32-n panel for this wave
  const int mp0 = mblk * 8 + wr * 4;    // first of 4 A-panels for this wave

  // fragment base pointers (lane*8 gives lhi*256 + l31*8: row=l31, k-half=lhi)
  const _Float16* pA[4];
#pragma unroll
  for (int mb = 0; mb < 4; ++mb)
    pA[mb] = Vp + ((size_t)(mp0 + mb) * 16) * 1024 + lane * 8;
  const _Float16* pB[4];
#pragma unroll
  for (int nb = 0; nb < 4; ++nb)
    pB[nb] = Bp + ((size_t)(p32 + nb) * 16) * 2048 + lane * 8;

  float16v acc[4][4];
#pragma unroll
  for (int mb = 0; mb < 4; ++mb)
#pragma unroll
    for (int nb = 0; nb < 4; ++nb) acc[mb][nb] = (float16v)0.0f;

  // 3-buffer ring, depth-2 prefetch: buf (k % 3) holds kstep k's operands.
  half8 ah[3][4], al[3][4], bh[3][4], bl[3][4];
#pragma unroll
  for (int pf = 0; pf < 2; ++pf) {          // prologue: ksteps 0 and 1
#pragma unroll
    for (int mb = 0; mb < 4; ++mb) {
      const _Float16* p = pA[mb] + pf * 1024;
      ah[pf][mb] = *(const half8*)p;
      al[pf][mb] = *(const half8*)(p + 512);
    }
#pragma unroll
    for (int nb = 0; nb < 4; ++nb) {
      const _Float16* p = pB[nb] + pf * 2048;
      bh[pf][nb] = *(const half8*)p;
      bl[pf][nb] = *(const half8*)(p + 1024);
    }
  }

#pragma unroll
  for (int kstep = 0; kstep < 16; ++kstep) {
    const int cur = kstep % 3;
    if (kstep < 14) {                        // prefetch kstep+2 into the buffer freed at kstep-1
      const int nxt = (kstep + 2) % 3;
      const int ko = kstep + 2;
#pragma unroll
      for (int mb = 0; mb < 4; ++mb) {
        const _Float16* p = pA[mb] + ko * 1024;
        ah[nxt][mb] = *(const half8*)p;
        al[nxt][mb] = *(const half8*)(p + 512);
      }
#pragma unroll
      for (int nb = 0; nb < 4; ++nb) {
        const _Float16* p = pB[nb] + ko * 2048;
        bh[nxt][nb] = *(const half8*)p;
        bl[nxt][nb] = *(const half8*)(p + 1024);
      }
    }
    // product-major, per-acc order identical to R9-R12 (bit-exact):
    // hi.hi, hi.lo, lo.hi within each kstep, ksteps ascending.
#pragma unroll
    for (int nb = 0; nb < 4; ++nb)
#pragma unroll
      for (int mb = 0; mb < 4; ++mb)
        acc[mb][nb] = __builtin_amdgcn_mfma_f32_32x32x16_f16(ah[cur][mb], bh[cur][nb], acc[mb][nb], 0, 0, 0);
#pragma unroll
    for (int nb = 0; nb < 4; ++nb)
#pragma unroll
      for (int mb = 0; mb < 4; ++mb)
        acc[mb][nb] = __builtin_amdgcn_mfma_f32_32x32x16_f16(ah[cur][mb], bl[cur][nb], acc[mb][nb], 0, 0, 0);
#pragma unroll
    for (int nb = 0; nb < 4; ++nb)
#pragma unroll
      for (int mb = 0; mb < 4; ++mb)
        acc[mb][nb] = __builtin_amdgcn_mfma_f32_32x32x16_f16(al[cur][mb], bh[cur][nb], acc[mb][nb], 0, 0, 0);
  }

  // ---- epilogue: diff = (v2 - 2*dot) + c2 (np order), argmin, tie -> lowest n ----
  float c2r[4];
#pragma unroll
  for (int nb = 0; nb < 4; ++nb) c2r[nb] = c2[n0 + wc * 128 + nb * 32 + l31];

  uint64_t* wbuf = (uint64_t*)smem_raw + wave * 1056;   // 32 rows x 33 u64, per wave

#pragma unroll
  for (int mb = 0; mb < 4; ++mb) {
#pragma unroll
    for (int r = 0; r < 16; ++r) {
      const int rowin = (r & 3) + 8 * (r >> 2) + 4 * lhi;
      const float v2m = v2[m0 + wr * 128 + mb * 32 + rowin];
      uint64_t b = ~0ULL;
#pragma unroll
      for (int nb = 0; nb < 4; ++nb) {
        const int n = n0 + wc * 128 + nb * 32 + l31;
        float dot = acc[mb][nb][r] * 0x1p-20f;            // exact pow2 unscale
        float dd  = __fadd_rn(__fsub_rn(v2m, 2.0f * dot), c2r[nb]);
        if (n == 0) dd = INFINITY;                        // exclude code 0
        uint64_t p = ((uint64_t)__float_as_uint(dd) << 32) | (uint32_t)n;
        if (p < b) b = p;                                 // dd>0 -> bits monotonic; nb asc keeps lowest n
      }
      wbuf[(r * 2 + lhi) * 33 + l31] = b;
    }
    __syncthreads();
    {
      const int f = lane >> 1, hf = lane & 1;
      const uint64_t* rp = wbuf + f * 33 + hf * 16;
      uint64_t m = rp[0];
#pragma unroll
      for (int i = 1; i < 16; ++i) { uint64_t v = rp[i]; if (v < m) m = v; }
      uint64_t o = __shfl_xor((unsigned long long)m, 1);
      if (o < m) m = o;
      if (hf == 0) {
        const int r_ = f >> 1, lh2 = f & 1;
        const int rowin = (r_ & 3) + 8 * (r_ >> 2) + 4 * lh2;
        red2[(wr * 128 + mb * 32 + rowin) * 2 + wc] = m;
      }
    }
    __syncthreads();
  }

  uint64_t a0 = red2[tid * 2], a1 = red2[tid * 2 + 1];
  atomicMin((unsigned long long*)&pk[m0 + tid], (unsigned long long)(a0 < a1 ? a0 : a1));
}

// ---- gather: one wave per query, no barriers ----
__global__ __launch_bounds__(256) void gather_kernel(
    const float* __restrict__ V, const float* __restrict__ W,
    const uint64_t* __restrict__ pk,
    float* __restrict__ out, float* __restrict__ outIdx,
    float* __restrict__ lossPartial)
{
  const int q = blockIdx.x * 4 + (threadIdx.x >> 6);
  const int l = threadIdx.x & 63;
  const uint64_t b = pk[q];             // wave-uniform broadcast load
  float4 vv = *(const float4*)(V + (size_t)q * D_DIM + l * 4);
  const float inv = 0.00390625f;
  bool ne = (vv.x != inv) | (vv.y != inv) | (vv.z != inv) | (vv.w != inv);
  const int idx = __ballot(ne) ? (int)(uint32_t)b : 0;
  float4 o4 = *(const float4*)(W + (size_t)idx * D_DIM + l * 4);
  *(float4*)(out + (size_t)q * D_DIM + l * 4) = o4;
  if (l == 0) outIdx[q] = (float)idx;
  float dx = o4.x - vv.x, dy = o4.y - vv.y, dz = o4.z - vv.z, dw = o4.w - vv.w;
  float s = dx * dx + dy * dy + dz * dz + dw * dw;
#pragma unroll
  for (int off = 32; off; off >>= 1) s += __shfl_xor(s, off);
  if (l == 0) lossPartial[q] = s;
}

__global__ __launch_bounds__(256) void finalize_kernel(
    const float* __restrict__ lossPartial, float* __restrict__ out)
{
  const int t = threadIdx.x;
  __shared__ float red[256];
  float s = 0.0f;
  for (int i = t; i < M_TOTAL; i += 256) s += lossPartial[i];
  red[t] = s;
  __syncthreads();
  for (int st = 128; st > 0; st >>= 1) {
    if (t < st) red[t] += red[t + st];
    __syncthreads();
  }
  if (t == 0) {
    out[0] = (float)((double)red[0] / (double)(M_TOTAL * D_DIM));  // loss
    out[1] = 0.0f;                                                 // used
  }
}

extern "C" void kernel_launch(void* const* d_in, const int* in_sizes, int n_in,
                              void* d_out, int out_size, void* d_ws, size_t ws_size,
                              hipStream_t stream) {
  const float* V = (const float*)d_in[0];   // 16384 x 256
  const float* W = (const float*)d_in[1];   // 4096 x 256
  float* out = (float*)d_out;

  // Packed V fragments live in d_out (exactly 16384*256*4 bytes); gather overwrites later.
  _Float16* Vp = (_Float16*)d_out;

  char* ws = (char*)d_ws;
  _Float16* Bp  = (_Float16*)(ws);                        // packed W frags: 8 MB region
  float*    c2  = (float*)(ws + 8388608);                 // 16 KB
  float*    v2  = (float*)(ws + 8388608 + 16384);         // 64 KB
  uint64_t* pk  = (uint64_t*)(ws + 8388608 + 16384 + 65536);   // 16384 u64 = 128 KB
  float* lossPartial = (float*)(ws + 8388608 + 16384 + 65536 + 131072);  // 64 KB

  prep_kernel<<<1280, 256, 0, stream>>>(V, W, Vp, Bp, v2, c2, pk);
  vq_mfma_kernel<<<1024, 256, 0, stream>>>(Vp, Bp, v2, c2, pk);
  gather_kernel<<<M_TOTAL / 4, 256, 0, stream>>>(V, W, pk, out, out + OUT_OFF_IDX, lossPartial);
  finalize_kernel<<<1, 256, 0, stream>>>(lossPartial, out + OUT_OFF_LOSS);
}